// Round 13
// baseline (231.926 us; speedup 1.0000x reference)
//
#include <hip/hip_runtime.h>
#include <hip/hip_bf16.h>
#include <float.h>

#define N_ORB 1024
#define KSEL 32
#define LEAK 0.01f

typedef float f32x2 __attribute__((ext_vector_type(2)));
// NOTE: never write (f32x2)(a, b) — comma-expr cast SPLATS b. Use f32x2{a,b}.

__device__ __forceinline__ float leaky(float x) { return x >= 0.0f ? x : LEAK * x; }

// R10-verified: top-32 of khot == top-32 of scores (order isomorphism);
// selection runs on monotone uint keys of scores.
__device__ __forceinline__ unsigned fkey(float f) {
  const unsigned u = __float_as_uint(f);
  return u ^ ((unsigned)((int)u >> 31) | 0x80000000u);
}

// packed fp32 fma (VOP3P). Per-half = same IEEE fma -> bit-exact (R6-verified).
__device__ __forceinline__ f32x2 pk_fma(f32x2 a, f32x2 b, f32x2 c) {
  f32x2 d;
  asm("v_pk_fma_f32 %0, %1, %2, %3" : "=v"(d) : "v"(a), "v"(b), "v"(c));
  return d;
}

// ---- DPP helpers ----
template <int CTRL, int RM>
__device__ __forceinline__ int dpp0_i(int v) {  // masked-off rows contribute 0
  return __builtin_amdgcn_update_dpp(0, v, CTRL, RM, 0xF, true);
}
template <int CTRL>
__device__ __forceinline__ float dpp_zero(float v) {
  return __int_as_float(
      __builtin_amdgcn_update_dpp(0, __float_as_int(v), CTRL, 0xF, 0xF, true));
}
__device__ __forceinline__ float rdlane(float v, int l) {
  return __int_as_float(__builtin_amdgcn_readlane(__float_as_int(v), l));
}

// full 64-lane float sum, uniform result
__device__ __forceinline__ float wave_sum64_dpp(float v) {
  v += dpp_zero<0x111>(v);
  v += dpp_zero<0x112>(v);
  v += dpp_zero<0x114>(v);
  v += dpp_zero<0x118>(v);
  v += dpp_zero<0x142>(v);
  v += dpp_zero<0x143>(v);
  return rdlane(v, 63);
}
// full 64-lane int sum, uniform result
__device__ __forceinline__ int wave_isum64(int v) {
  v += dpp0_i<0x111, 0xF>(v);
  v += dpp0_i<0x112, 0xF>(v);
  v += dpp0_i<0x114, 0xF>(v);
  v += dpp0_i<0x118, 0xF>(v);
  v += dpp0_i<0x142, 0xF>(v);
  v += dpp0_i<0x143, 0xF>(v);
  return __builtin_amdgcn_readlane(v, 63);
}
// 64-lane inclusive prefix sum (int), per-lane result
__device__ __forceinline__ int wave_iscan64(int v) {
  v += dpp0_i<0x111, 0xF>(v);
  v += dpp0_i<0x112, 0xF>(v);
  v += dpp0_i<0x114, 0xF>(v);
  v += dpp0_i<0x118, 0xF>(v);
  v += dpp0_i<0x142, 0xA>(v);
  v += dpp0_i<0x143, 0xC>(v);
  return v;
}

// Tie path (cold). jax stable tie semantics: all >T, then ==T in ascending
// global index ((lane<<4)|slot). Operates on monotone uint keys.
__device__ unsigned tie_mask16u(const unsigned K[16], unsigned T, int lane) {
  unsigned gt = 0, eq = 0;
#pragma unroll
  for (int i = 0; i < 16; ++i) {
    gt |= (K[i] > T ? 1u : 0u) << i;
    eq |= (K[i] == T ? 1u : 0u) << i;
  }
  const int n_gt = wave_isum64(__popc(gt));
  const int m = 32 - n_gt;  // uniform, >= 1 by search invariant
  const int pe = __popc(eq);
  const int be = wave_iscan64(pe) - pe;
  int need = m - be;
  need = need < 0 ? 0 : (need > pe ? pe : need);
  unsigned tk = 0;
  unsigned em = eq;
  for (int guard = 0; guard < 16; ++guard) {
    if (!__any(need > 0)) break;
    if (need > 0) {
      const int bpos = __ffs(em) - 1;
      tk |= 1u << bpos;
      em &= em - 1;
      --need;
    }
  }
  return gt | tk;
}

// Top-32 for ONE row on uint keys, binary search from bit 31,
// ballot+popcll counting, early exit when exact.
__device__ unsigned top32_mask1u(const unsigned K[16], int lane) {
  unsigned lo = 0;
  bool ex = false;
  for (int b = 31; b >= 0; --b) {
    const unsigned cv = lo | (1u << b);
    int c = 0;
#pragma unroll
    for (int i = 0; i < 16; ++i) c += __popcll(__ballot(K[i] >= cv));
    if (c >= 32) {
      lo = cv;
      if (c == 32) { ex = true; break; }
    }
  }
  if (ex) {
    unsigned mk = 0;
#pragma unroll
    for (int i = 0; i < 16; ++i) mk |= (K[i] >= lo ? 1u : 0u) << i;
    return mk;
  }
  return tie_mask16u(K, lo, lane);
}

// Compact the 32 selected global indices into dst[0..31], ascending order.
__device__ __forceinline__ void compact_idx(unsigned mask, int lane,
                                            int* __restrict__ dst) {
  const int pe = __popc(mask);
  int base = wave_iscan64(pe) - pe;
  unsigned m = mask;
  while (m) {
    const int s = __ffs(m) - 1;
    m &= m - 1;
    dst[base++] = (lane << 4) | s;
  }
}

__device__ __forceinline__ void write_half(float* __restrict__ dst,
                                           unsigned mask, int lane) {
  float4* o4 = (float4*)dst;
#pragma unroll
  for (int q = 0; q < 4; ++q) {
    float4 o;
    o.x = ((mask >> (4 * q + 0)) & 1) ? 1.0f : 0.0f;
    o.y = ((mask >> (4 * q + 1)) & 1) ? 1.0f : 0.0f;
    o.z = ((mask >> (4 * q + 2)) & 1) ? 1.0f : 0.0f;
    o.w = ((mask >> (4 * q + 3)) & 1) ? 1.0f : 0.0f;
    o4[lane * 4 + q] = o;
  }
}

// ws layout (floats): [0,1024) alpha const logits; [1024,1152) beta base
// dots; [1152,1280) h1a; [1280,1344) h2a.

// ---- precompute, stage 1 (grid 256): the two length-1024 dot layers ----
extern "C" __global__ void pcfs_pre1(const float* __restrict__ ba,
                                     const float* __restrict__ W1a,
                                     const float* __restrict__ b1a,
                                     const float* __restrict__ bb,
                                     const float* __restrict__ W1b,
                                     float* __restrict__ ws) {
  const int b = blockIdx.x;
  const int t = threadIdx.x;
  float acc = 0.0f;
  if (b < 128) {
#pragma unroll
    for (int j = t; j < N_ORB; j += 256) acc += ba[j] * W1a[j * 128 + b];
  } else {
    const int n = b - 128;
#pragma unroll
    for (int j = t; j < N_ORB; j += 256) acc += bb[j] * W1b[j * 128 + n];
  }
  __shared__ float red[4];
  float wsum = wave_sum64_dpp(acc);
  if ((t & 63) == 0) red[t >> 6] = wsum;
  __syncthreads();
  if (t == 0) {
    float tot = red[0] + red[1] + red[2] + red[3];
    if (b < 128)
      ws[1152 + b] = leaky(tot + b1a[b]);
    else
      ws[N_ORB + (b - 128)] = tot;
  }
}

// ---- precompute, stage 2a (1 block x 64): h2 = leaky(h1 @ W2a + b2a) ----
extern "C" __global__ void pcfs_pre2a(const float* __restrict__ W2a,
                                      const float* __restrict__ b2a,
                                      float* __restrict__ ws) {
  const int t = threadIdx.x;  // 64
  float acc = b2a[t];
#pragma unroll 8
  for (int n = 0; n < 128; ++n) acc = __builtin_fmaf(ws[1152 + n], W2a[n * 64 + t], acc);
  ws[1280 + t] = leaky(acc);
}

// ---- precompute, stage 2b (grid 4 x 256): alpha logits = h2 @ W3a + b3a
// + base_a, coalesced row-major W3a reads ----
extern "C" __global__ void pcfs_pre2b(const float* __restrict__ ba,
                                      const float* __restrict__ W3a,
                                      const float* __restrict__ b3a,
                                      float* __restrict__ ws) {
  __shared__ float h2s[64];
  const int t = threadIdx.x;
  const int o = blockIdx.x * 256 + t;
  if (t < 64) h2s[t] = ws[1280 + t];
  __syncthreads();
  float acc = b3a[o] + ba[o];
#pragma unroll 8
  for (int m = 0; m < 64; ++m) acc = __builtin_fmaf(h2s[m], W3a[m * N_ORB + o], acc);
  ws[o] = acc;
}

// R13: ONE row per wave (R11 had 2). R11/R12 counters: occupancy is
// GRID-limited (1024 blocks = 4 blocks/CU exactly), per-wave duty ~13%,
// busy 43% — latency-bound with capped TLP. Halving rows/wave doubles the
// grid (2048 blocks -> 8 blocks/CU, 32 waves/CU) without changing total
// issue; per-wave W3b cost unchanged (cooperative column split). Scalar
// per-row math = identical IEEE op order as R11's per-half lanes ->
// bit-exact. LDS: lgt 16KB + h2sh 1KB + sidx 0.5KB = 17.9KB -> 8 blocks/CU;
// launch_bounds(256,8) pins the <=64-VGPR tier (R3-verified).
extern "C" __global__ void __launch_bounds__(256, 8) pcfs_sampler(
    const float* __restrict__ ws, const float* __restrict__ Wc,
    const float* __restrict__ bc, const float* __restrict__ W1b,
    const float* __restrict__ b1b, const float* __restrict__ W2b,
    const float* __restrict__ b2b, const float* __restrict__ W3b,
    const float* __restrict__ b3b, const float* __restrict__ bb,
    const float* __restrict__ g_alpha, const float* __restrict__ g_beta,
    float* __restrict__ out, int B) {
  __shared__ int sidx[4][32];       // per-wave: 32 selected alpha indices
  __shared__ float lgt[4 * N_ORB];  // 16 KB: block's 4 rows of beta logits
  __shared__ float h2sh[4 * 64];    // 1 KB: h2 exchange (one row per wave)
  const int tid = threadIdx.x;
  const int wave = tid >> 6;
  const int lane = tid & 63;
  const int row = blockIdx.x * 4 + wave;
  // No early return: all threads reach the barriers. Inactive waves compute
  // on clamped rows and skip output writes.
  const bool active = (row < B);
  const int r0 = active ? row : 0;

  // ---- prefetch g_beta into registers NOW (R11-verified position): drains
  // under the alpha+MLP phases ----
  float4 gb[4];
  {
    const float4* g4 = (const float4*)(g_beta + (size_t)r0 * N_ORB);
#pragma unroll
    for (int q = 0; q < 4; ++q) gb[q] = g4[lane * 4 + q];
  }

  // ---- alpha selection: keys of scores = const_logits + gumbel ----
  unsigned ka[16];
  {
    const float4* c4 = (const float4*)ws;
    const float4* g4 = (const float4*)(g_alpha + (size_t)r0 * N_ORB);
#pragma unroll
    for (int q = 0; q < 4; ++q) {
      float4 c = c4[lane * 4 + q];
      float4 g = g4[lane * 4 + q];
      ka[4 * q + 0] = fkey(c.x + g.x);
      ka[4 * q + 1] = fkey(c.y + g.y);
      ka[4 * q + 2] = fkey(c.z + g.z);
      ka[4 * q + 3] = fkey(c.w + g.w);
    }
  }
  const unsigned am = top32_mask1u(ka, lane);

  // write alpha half (hard config: exact 0/1)
  if (active) write_half(out + (size_t)row * (2 * N_ORB), am, lane);

  // ---- ctx = alpha_config @ Wc + bc (LDS compact + fixed 32-trip) ----
  compact_idx(am, lane, sidx[wave]);
  const int vi = sidx[wave][lane & 31];
  float ctx = bc[lane & 31];
#pragma unroll
  for (int r = 0; r < 32; ++r) {
    const int i0 = __builtin_amdgcn_readlane(vi, r);  // uniform
    ctx += Wc[i0 * 32 + (lane & 31)];
  }

  // ---- h1 = leaky(base_b@W1b[0:1024] + ctx@W1b[1024:1056] + b1b) ----
  float h1a = b1b[lane] + ws[N_ORB + lane];
  float h1b = b1b[lane + 64] + ws[N_ORB + lane + 64];
#pragma unroll 4
  for (int c = 0; c < 32; ++c) {
    const float cv = rdlane(ctx, c);
    const float* wr = W1b + (size_t)(N_ORB + c) * 128;
    h1a = __builtin_fmaf(wr[lane], cv, h1a);
    h1b = __builtin_fmaf(wr[lane + 64], cv, h1b);
  }
  h1a = leaky(h1a);
  h1b = leaky(h1b);

  // ---- h2 = leaky(h1 @ W2b + b2b): 4 partial accumulators ----
  float p0 = b2b[lane], p1 = 0.0f, p2 = 0.0f, p3 = 0.0f;
#pragma unroll 4
  for (int n = 0; n < 64; n += 4) {
    p0 = __builtin_fmaf(W2b[(n + 0) * 64 + lane], rdlane(h1a, n + 0), p0);
    p1 = __builtin_fmaf(W2b[(n + 1) * 64 + lane], rdlane(h1a, n + 1), p1);
    p2 = __builtin_fmaf(W2b[(n + 2) * 64 + lane], rdlane(h1a, n + 2), p2);
    p3 = __builtin_fmaf(W2b[(n + 3) * 64 + lane], rdlane(h1a, n + 3), p3);
  }
#pragma unroll 4
  for (int n = 0; n < 64; n += 4) {
    p0 = __builtin_fmaf(W2b[(n + 64 + 0) * 64 + lane], rdlane(h1b, n + 0), p0);
    p1 = __builtin_fmaf(W2b[(n + 64 + 1) * 64 + lane], rdlane(h1b, n + 1), p1);
    p2 = __builtin_fmaf(W2b[(n + 64 + 2) * 64 + lane], rdlane(h1b, n + 2), p2);
    p3 = __builtin_fmaf(W2b[(n + 64 + 3) * 64 + lane], rdlane(h1b, n + 3), p3);
  }
  float h2v = (p0 + p1) + (p2 + p3);
  h2v = leaky(h2v);

  // ---- share h2 across the block's 4 waves (one row each) ----
  h2sh[wave * 64 + lane] = h2v;
  __syncthreads();
  const float hh0 = h2sh[0 * 64 + lane];
  const float hh1 = h2sh[1 * 64 + lane];
  const float hh2 = h2sh[2 * 64 + lane];
  const float hh3 = h2sh[3 * 64 + lane];

  // ---- cooperative beta matmul: wave owns columns [wave*256, wave*256+256);
  // lane owns 4 cols (one float4) for all 4 block rows. Rows packed 2/f32x2
  // (rows 0,1 -> .x,.y of acc2[0]; rows 2,3 -> acc2[1]). ----
  const int cbase = wave * 64 + lane;  // float4 index within a 1024-col row
  f32x2 acc2[2][4];
  {
    const float4 b3v = ((const float4*)b3b)[cbase];
#pragma unroll
    for (int rp = 0; rp < 2; ++rp) {
      acc2[rp][0] = f32x2{b3v.x, b3v.x};
      acc2[rp][1] = f32x2{b3v.y, b3v.y};
      acc2[rp][2] = f32x2{b3v.z, b3v.z};
      acc2[rp][3] = f32x2{b3v.w, b3v.w};
    }
  }
  {
    const float4* w34 = (const float4*)W3b;
#pragma unroll 4
    for (int m = 0; m < 64; ++m) {
      const float4 wv = w34[(m << 8) + cbase];
      const f32x2 h01 = f32x2{rdlane(hh0, m), rdlane(hh1, m)};
      const f32x2 h23 = f32x2{rdlane(hh2, m), rdlane(hh3, m)};
      acc2[0][0] = pk_fma(f32x2{wv.x, wv.x}, h01, acc2[0][0]);
      acc2[0][1] = pk_fma(f32x2{wv.y, wv.y}, h01, acc2[0][1]);
      acc2[0][2] = pk_fma(f32x2{wv.z, wv.z}, h01, acc2[0][2]);
      acc2[0][3] = pk_fma(f32x2{wv.w, wv.w}, h01, acc2[0][3]);
      acc2[1][0] = pk_fma(f32x2{wv.x, wv.x}, h23, acc2[1][0]);
      acc2[1][1] = pk_fma(f32x2{wv.y, wv.y}, h23, acc2[1][1]);
      acc2[1][2] = pk_fma(f32x2{wv.z, wv.z}, h23, acc2[1][2]);
      acc2[1][3] = pk_fma(f32x2{wv.w, wv.w}, h23, acc2[1][3]);
    }
  }
  // redistribute logits: row-major [4][1024] in LDS, contiguous b128 writes
#pragma unroll
  for (int rp = 0; rp < 2; ++rp) {
    float4 ex, ey;
    ex.x = acc2[rp][0].x; ex.y = acc2[rp][1].x; ex.z = acc2[rp][2].x; ex.w = acc2[rp][3].x;
    ey.x = acc2[rp][0].y; ey.y = acc2[rp][1].y; ey.z = acc2[rp][2].y; ey.w = acc2[rp][3].y;
    ((float4*)(lgt + (2 * rp) * N_ORB))[cbase] = ex;
    ((float4*)(lgt + (2 * rp + 1) * N_ORB))[cbase] = ey;
  }
  __syncthreads();

  // readback own row + base_b + gumbel (prefetched) -> keys
  unsigned kb[16];
  {
    const float4* lr = (const float4*)(lgt + wave * N_ORB);
    const float4* bb4 = (const float4*)bb;
#pragma unroll
    for (int q = 0; q < 4; ++q) {
      const float4 a = lr[lane * 4 + q];
      const float4 b = bb4[lane * 4 + q];
      const float4 g = gb[q];
      kb[4 * q + 0] = fkey(a.x + b.x + g.x);
      kb[4 * q + 1] = fkey(a.y + b.y + g.y);
      kb[4 * q + 2] = fkey(a.z + b.z + g.z);
      kb[4 * q + 3] = fkey(a.w + b.w + g.w);
    }
  }
  const unsigned bm = top32_mask1u(kb, lane);

  if (active) write_half(out + (size_t)row * (2 * N_ORB) + N_ORB, bm, lane);
}

extern "C" void kernel_launch(void* const* d_in, const int* in_sizes, int n_in,
                              void* d_out, int out_size, void* d_ws, size_t ws_size,
                              hipStream_t stream) {
  const float* ba  = (const float*)d_in[0];
  const float* W1a = (const float*)d_in[1];
  const float* b1a = (const float*)d_in[2];
  const float* W2a = (const float*)d_in[3];
  const float* b2a = (const float*)d_in[4];
  const float* W3a = (const float*)d_in[5];
  const float* b3a = (const float*)d_in[6];
  const float* bb  = (const float*)d_in[7];
  const float* Wc  = (const float*)d_in[8];
  const float* bc  = (const float*)d_in[9];
  const float* W1b = (const float*)d_in[10];
  const float* b1b = (const float*)d_in[11];
  const float* W2b = (const float*)d_in[12];
  const float* b2b = (const float*)d_in[13];
  const float* W3b = (const float*)d_in[14];
  const float* b3b = (const float*)d_in[15];
  const float* ga  = (const float*)d_in[16];
  const float* gbt = (const float*)d_in[17];
  const int B = in_sizes[16] / N_ORB;
  float* ws = (float*)d_ws;

  hipLaunchKernelGGL(pcfs_pre1, dim3(256), dim3(256), 0, stream,
                     ba, W1a, b1a, bb, W1b, ws);
  hipLaunchKernelGGL(pcfs_pre2a, dim3(1), dim3(64), 0, stream,
                     W2a, b2a, ws);
  hipLaunchKernelGGL(pcfs_pre2b, dim3(4), dim3(256), 0, stream,
                     ba, W3a, b3a, ws);
  hipLaunchKernelGGL(pcfs_sampler, dim3((B + 3) / 4), dim3(256), 0, stream,
                     ws, Wc, bc, W1b, b1b, W2b, b2b, W3b, b3b, bb,
                     ga, gbt, (float*)d_out, B);
}

// Round 14
// 229.679 us; speedup vs baseline: 1.0098x; 1.0098x over previous
//
#include <hip/hip_runtime.h>
#include <hip/hip_bf16.h>
#include <float.h>

#define N_ORB 1024
#define KSEL 32
#define LEAK 0.01f

typedef float f32x2 __attribute__((ext_vector_type(2)));
// NOTE: never write (f32x2)(a, b) — comma-expr cast SPLATS b. Use f32x2{a,b}.

__device__ __forceinline__ float leaky(float x) { return x >= 0.0f ? x : LEAK * x; }

// R10-verified: top-32 of khot == top-32 of scores (order isomorphism proof in
// session log); selection runs on monotone uint keys of scores.
__device__ __forceinline__ unsigned fkey(float f) {
  const unsigned u = __float_as_uint(f);
  return u ^ ((unsigned)((int)u >> 31) | 0x80000000u);
}

// packed fp32 fma (VOP3P). Per-half = same IEEE fma -> bit-exact (R6-verified).
__device__ __forceinline__ f32x2 pk_fma(f32x2 a, f32x2 b, f32x2 c) {
  f32x2 d;
  asm("v_pk_fma_f32 %0, %1, %2, %3" : "=v"(d) : "v"(a), "v"(b), "v"(c));
  return d;
}

// ---- DPP helpers ----
template <int CTRL, int RM>
__device__ __forceinline__ int dpp0_i(int v) {  // masked-off rows contribute 0
  return __builtin_amdgcn_update_dpp(0, v, CTRL, RM, 0xF, true);
}
template <int CTRL>
__device__ __forceinline__ float dpp_zero(float v) {
  return __int_as_float(
      __builtin_amdgcn_update_dpp(0, __float_as_int(v), CTRL, 0xF, 0xF, true));
}
__device__ __forceinline__ float rdlane(float v, int l) {
  return __int_as_float(__builtin_amdgcn_readlane(__float_as_int(v), l));
}

// full 64-lane float sum, uniform result
__device__ __forceinline__ float wave_sum64_dpp(float v) {
  v += dpp_zero<0x111>(v);
  v += dpp_zero<0x112>(v);
  v += dpp_zero<0x114>(v);
  v += dpp_zero<0x118>(v);
  v += dpp_zero<0x142>(v);
  v += dpp_zero<0x143>(v);
  return rdlane(v, 63);
}
// full 64-lane int sum, uniform result
__device__ __forceinline__ int wave_isum64(int v) {
  v += dpp0_i<0x111, 0xF>(v);
  v += dpp0_i<0x112, 0xF>(v);
  v += dpp0_i<0x114, 0xF>(v);
  v += dpp0_i<0x118, 0xF>(v);
  v += dpp0_i<0x142, 0xF>(v);
  v += dpp0_i<0x143, 0xF>(v);
  return __builtin_amdgcn_readlane(v, 63);
}
// 64-lane inclusive prefix sum (int), per-lane result
__device__ __forceinline__ int wave_iscan64(int v) {
  v += dpp0_i<0x111, 0xF>(v);
  v += dpp0_i<0x112, 0xF>(v);
  v += dpp0_i<0x114, 0xF>(v);
  v += dpp0_i<0x118, 0xF>(v);
  v += dpp0_i<0x142, 0xA>(v);
  v += dpp0_i<0x143, 0xC>(v);
  return v;
}

// Tie path (cold). jax stable tie semantics: all >T, then ==T in ascending
// global index ((lane<<4)|slot). Operates on monotone uint keys.
__device__ unsigned tie_mask16u(const unsigned K[16], unsigned T, int lane) {
  unsigned gt = 0, eq = 0;
#pragma unroll
  for (int i = 0; i < 16; ++i) {
    gt |= (K[i] > T ? 1u : 0u) << i;
    eq |= (K[i] == T ? 1u : 0u) << i;
  }
  const int n_gt = wave_isum64(__popc(gt));
  const int m = 32 - n_gt;  // uniform, >= 1 by search invariant
  const int pe = __popc(eq);
  const int be = wave_iscan64(pe) - pe;
  int need = m - be;
  need = need < 0 ? 0 : (need > pe ? pe : need);
  unsigned tk = 0;
  unsigned em = eq;
  for (int guard = 0; guard < 16; ++guard) {
    if (!__any(need > 0)) break;
    if (need > 0) {
      const int bpos = __ffs(em) - 1;
      tk |= 1u << bpos;
      em &= em - 1;
      --need;
    }
  }
  return gt | tk;
}

// Top-32 for two rows on uint keys, joint binary search from bit 31,
// ballot+popcll counting, early exit when both exact.
__device__ void top32_mask2u(const unsigned K0[16], const unsigned K1[16],
                             int lane, unsigned& m0, unsigned& m1) {
  unsigned lo0 = 0, lo1 = 0;
  bool ex0 = false, ex1 = false;
  for (int b = 31; b >= 0; --b) {
    const unsigned c0v = lo0 | (1u << b);
    const unsigned c1v = lo1 | (1u << b);
    int c0 = 0, c1 = 0;
#pragma unroll
    for (int i = 0; i < 16; ++i) {
      c0 += __popcll(__ballot(K0[i] >= c0v));
      c1 += __popcll(__ballot(K1[i] >= c1v));
    }
    if (!ex0 && c0 >= 32) { lo0 = c0v; ex0 = (c0 == 32); }
    if (!ex1 && c1 >= 32) { lo1 = c1v; ex1 = (c1 == 32); }
    if (ex0 && ex1) break;
  }

  if (ex0) {
    unsigned mk = 0;
#pragma unroll
    for (int i = 0; i < 16; ++i) mk |= (K0[i] >= lo0 ? 1u : 0u) << i;
    m0 = mk;
  } else {
    m0 = tie_mask16u(K0, lo0, lane);
  }
  if (ex1) {
    unsigned mk = 0;
#pragma unroll
    for (int i = 0; i < 16; ++i) mk |= (K1[i] >= lo1 ? 1u : 0u) << i;
    m1 = mk;
  } else {
    m1 = tie_mask16u(K1, lo1, lane);
  }
}

// Compact the 32 selected global indices into dst[0..31], ascending order.
__device__ __forceinline__ void compact_idx(unsigned mask, int lane,
                                            int* __restrict__ dst) {
  const int pe = __popc(mask);
  int base = wave_iscan64(pe) - pe;
  unsigned m = mask;
  while (m) {
    const int s = __ffs(m) - 1;
    m &= m - 1;
    dst[base++] = (lane << 4) | s;
  }
}

__device__ __forceinline__ void write_half(float* __restrict__ dst,
                                           unsigned mask, int lane) {
  float4* o4 = (float4*)dst;
#pragma unroll
  for (int q = 0; q < 4; ++q) {
    float4 o;
    o.x = ((mask >> (4 * q + 0)) & 1) ? 1.0f : 0.0f;
    o.y = ((mask >> (4 * q + 1)) & 1) ? 1.0f : 0.0f;
    o.z = ((mask >> (4 * q + 2)) & 1) ? 1.0f : 0.0f;
    o.w = ((mask >> (4 * q + 3)) & 1) ? 1.0f : 0.0f;
    o4[lane * 4 + q] = o;
  }
}

// ws layout (floats): [0,1024) alpha const logits; [1024,1152) beta base
// dots; [1152,1280) h1a; [1280,1344) h2a.

// ---- precompute, stage 1 (grid 256): the two length-1024 dot layers ----
extern "C" __global__ void pcfs_pre1(const float* __restrict__ ba,
                                     const float* __restrict__ W1a,
                                     const float* __restrict__ b1a,
                                     const float* __restrict__ bb,
                                     const float* __restrict__ W1b,
                                     float* __restrict__ ws) {
  const int b = blockIdx.x;
  const int t = threadIdx.x;
  float acc = 0.0f;
  if (b < 128) {
#pragma unroll
    for (int j = t; j < N_ORB; j += 256) acc += ba[j] * W1a[j * 128 + b];
  } else {
    const int n = b - 128;
#pragma unroll
    for (int j = t; j < N_ORB; j += 256) acc += bb[j] * W1b[j * 128 + n];
  }
  __shared__ float red[4];
  float wsum = wave_sum64_dpp(acc);
  if ((t & 63) == 0) red[t >> 6] = wsum;
  __syncthreads();
  if (t == 0) {
    float tot = red[0] + red[1] + red[2] + red[3];
    if (b < 128)
      ws[1152 + b] = leaky(tot + b1a[b]);
    else
      ws[N_ORB + (b - 128)] = tot;
  }
}

// ---- precompute, stage 2a (1 block x 64): h2 = leaky(h1 @ W2a + b2a) ----
extern "C" __global__ void pcfs_pre2a(const float* __restrict__ W2a,
                                      const float* __restrict__ b2a,
                                      float* __restrict__ ws) {
  const int t = threadIdx.x;  // 64
  float acc = b2a[t];
#pragma unroll 8
  for (int n = 0; n < 128; ++n) acc = __builtin_fmaf(ws[1152 + n], W2a[n * 64 + t], acc);
  ws[1280 + t] = leaky(acc);
}

// ---- precompute, stage 2b (grid 4 x 256): alpha logits = h2 @ W3a + b3a
// + base_a, coalesced row-major W3a reads ----
extern "C" __global__ void pcfs_pre2b(const float* __restrict__ ba,
                                      const float* __restrict__ W3a,
                                      const float* __restrict__ b3a,
                                      float* __restrict__ ws) {
  __shared__ float h2s[64];
  const int t = threadIdx.x;
  const int o = blockIdx.x * 256 + t;
  if (t < 64) h2s[t] = ws[1280 + t];
  __syncthreads();
  float acc = b3a[o] + ba[o];
#pragma unroll 8
  for (int m = 0; m < 64; ++m) acc = __builtin_fmaf(h2s[m], W3a[m * N_ORB + o], acc);
  ws[o] = acc;
}

// One wave per PAIR of batch rows. CHAMPION CONFIG (R11, 229.88 us total,
// sampler 90.3 us): cooperative column-split W3b matmul — wave w computes
// column quarter [256w,256w+256) of ALL 8 block rows from L2 (64 coalesced
// float4 loads; no staging); h2 shared via 2KB LDS + readlane; logits
// redistributed via 32KB LDS. R12 (prefetch moved + waves_per_eu) regressed
// -13us; R13 (1 row/wave, 2x occupancy) tied — time tracks total VALU issue
// at ~46% effective rate, TLP-invariant (R3/R13 falsifications).
extern "C" __global__ void __launch_bounds__(256, 4) pcfs_sampler(
    const float* __restrict__ ws, const float* __restrict__ Wc,
    const float* __restrict__ bc, const float* __restrict__ W1b,
    const float* __restrict__ b1b, const float* __restrict__ W2b,
    const float* __restrict__ b2b, const float* __restrict__ W3b,
    const float* __restrict__ b3b, const float* __restrict__ bb,
    const float* __restrict__ g_alpha, const float* __restrict__ g_beta,
    float* __restrict__ out, int B) {
  __shared__ int sidx[4][64];       // per-wave: [0..31]=row0, [32..63]=row1
  __shared__ float lgt[8 * N_ORB];  // 32 KB: block's 8 rows of beta logits
  __shared__ f32x2 h2sh[4 * 64];    // 2 KB: h2 exchange (pair per wave)
  const int tid = threadIdx.x;
  const int wave = tid >> 6;
  const int lane = tid & 63;
  const int pair = blockIdx.x * 4 + wave;
  const int row0 = pair * 2;
  // No early return: all threads reach the barriers. Inactive waves compute
  // on clamped rows and skip output writes.
  const bool active = (row0 < B);
  const bool have1 = active && (row0 + 1 < B);
  const int r0 = active ? row0 : 0;
  const int r1 = have1 ? row0 + 1 : r0;

  // ---- prefetch g_beta into registers: drains during alpha+MLP phases ----
  float4 gb0[4], gb1[4];
  {
    const float4* g40 = (const float4*)(g_beta + (size_t)r0 * N_ORB);
    const float4* g41 = (const float4*)(g_beta + (size_t)r1 * N_ORB);
#pragma unroll
    for (int q = 0; q < 4; ++q) {
      gb0[q] = g40[lane * 4 + q];
      gb1[q] = g41[lane * 4 + q];
    }
  }

  // ---- alpha selection: keys of scores = const_logits + gumbel ----
  unsigned ka0[16], ka1[16];
  {
    const float4* c4 = (const float4*)ws;
    const float4* g40 = (const float4*)(g_alpha + (size_t)r0 * N_ORB);
    const float4* g41 = (const float4*)(g_alpha + (size_t)r1 * N_ORB);
#pragma unroll
    for (int q = 0; q < 4; ++q) {
      float4 c = c4[lane * 4 + q];
      float4 g0 = g40[lane * 4 + q];
      float4 g1 = g41[lane * 4 + q];
      ka0[4 * q + 0] = fkey(c.x + g0.x); ka1[4 * q + 0] = fkey(c.x + g1.x);
      ka0[4 * q + 1] = fkey(c.y + g0.y); ka1[4 * q + 1] = fkey(c.y + g1.y);
      ka0[4 * q + 2] = fkey(c.z + g0.z); ka1[4 * q + 2] = fkey(c.z + g1.z);
      ka0[4 * q + 3] = fkey(c.w + g0.w); ka1[4 * q + 3] = fkey(c.w + g1.w);
    }
  }
  unsigned am0, am1;
  top32_mask2u(ka0, ka1, lane, am0, am1);

  // write alpha halves (hard config: exact 0/1)
  if (active) write_half(out + (size_t)row0 * (2 * N_ORB), am0, lane);
  if (have1) write_half(out + (size_t)(row0 + 1) * (2 * N_ORB), am1, lane);

  // ---- ctx = alpha_config @ Wc + bc, per row (LDS compact + fixed trip) ----
  compact_idx(am0, lane, &sidx[wave][0]);
  compact_idx(am1, lane, &sidx[wave][32]);
  const int vi0 = sidx[wave][lane & 31];
  const int vi1 = sidx[wave][32 + (lane & 31)];
  const float bcv = bc[lane & 31];
  float ctx0 = bcv, ctx1 = bcv;
#pragma unroll
  for (int r = 0; r < 32; ++r) {
    const int i0 = __builtin_amdgcn_readlane(vi0, r);  // uniform
    const int i1 = __builtin_amdgcn_readlane(vi1, r);
    ctx0 += Wc[i0 * 32 + (lane & 31)];
    ctx1 += Wc[i1 * 32 + (lane & 31)];
  }

  // ---- h1 = leaky(base_b@W1b[0:1024] + ctx@W1b[1024:1056] + b1b) ----
  f32x2 h1a, h1b_;
  {
    const float ia = b1b[lane] + ws[N_ORB + lane];
    const float ib = b1b[lane + 64] + ws[N_ORB + lane + 64];
    h1a = f32x2{ia, ia};
    h1b_ = f32x2{ib, ib};
  }
#pragma unroll 4
  for (int c = 0; c < 32; ++c) {
    const f32x2 cv = f32x2{rdlane(ctx0, c), rdlane(ctx1, c)};
    const float* wr = W1b + (size_t)(N_ORB + c) * 128;
    const float wa = wr[lane], wb = wr[lane + 64];
    h1a = __builtin_elementwise_fma(f32x2{wa, wa}, cv, h1a);
    h1b_ = __builtin_elementwise_fma(f32x2{wb, wb}, cv, h1b_);
  }
  h1a = f32x2{leaky(h1a.x), leaky(h1a.y)};
  h1b_ = f32x2{leaky(h1b_.x), leaky(h1b_.y)};

  // ---- h2 = leaky(h1 @ W2b + b2b): 4 partial accumulators ----
  f32x2 h2p0, h2p1, h2p2, h2p3;
  {
    const float i2 = b2b[lane];
    h2p0 = f32x2{i2, i2};
    h2p1 = f32x2{0.0f, 0.0f};
    h2p2 = f32x2{0.0f, 0.0f};
    h2p3 = f32x2{0.0f, 0.0f};
  }
#pragma unroll 4
  for (int n = 0; n < 64; n += 4) {
    const f32x2 v0 = f32x2{rdlane(h1a.x, n + 0), rdlane(h1a.y, n + 0)};
    const f32x2 v1 = f32x2{rdlane(h1a.x, n + 1), rdlane(h1a.y, n + 1)};
    const f32x2 v2 = f32x2{rdlane(h1a.x, n + 2), rdlane(h1a.y, n + 2)};
    const f32x2 v3 = f32x2{rdlane(h1a.x, n + 3), rdlane(h1a.y, n + 3)};
    const float w0 = W2b[(n + 0) * 64 + lane];
    const float w1 = W2b[(n + 1) * 64 + lane];
    const float w2 = W2b[(n + 2) * 64 + lane];
    const float w3 = W2b[(n + 3) * 64 + lane];
    h2p0 = __builtin_elementwise_fma(f32x2{w0, w0}, v0, h2p0);
    h2p1 = __builtin_elementwise_fma(f32x2{w1, w1}, v1, h2p1);
    h2p2 = __builtin_elementwise_fma(f32x2{w2, w2}, v2, h2p2);
    h2p3 = __builtin_elementwise_fma(f32x2{w3, w3}, v3, h2p3);
  }
#pragma unroll 4
  for (int n = 0; n < 64; n += 4) {
    const f32x2 v0 = f32x2{rdlane(h1b_.x, n + 0), rdlane(h1b_.y, n + 0)};
    const f32x2 v1 = f32x2{rdlane(h1b_.x, n + 1), rdlane(h1b_.y, n + 1)};
    const f32x2 v2 = f32x2{rdlane(h1b_.x, n + 2), rdlane(h1b_.y, n + 2)};
    const f32x2 v3 = f32x2{rdlane(h1b_.x, n + 3), rdlane(h1b_.y, n + 3)};
    const float w0 = W2b[(n + 64 + 0) * 64 + lane];
    const float w1 = W2b[(n + 64 + 1) * 64 + lane];
    const float w2 = W2b[(n + 64 + 2) * 64 + lane];
    const float w3 = W2b[(n + 64 + 3) * 64 + lane];
    h2p0 = __builtin_elementwise_fma(f32x2{w0, w0}, v0, h2p0);
    h2p1 = __builtin_elementwise_fma(f32x2{w1, w1}, v1, h2p1);
    h2p2 = __builtin_elementwise_fma(f32x2{w2, w2}, v2, h2p2);
    h2p3 = __builtin_elementwise_fma(f32x2{w3, w3}, v3, h2p3);
  }
  f32x2 h2v = (h2p0 + h2p1) + (h2p2 + h2p3);
  h2v = f32x2{leaky(h2v.x), leaky(h2v.y)};

  // ---- share h2 across the block's 4 waves ----
  h2sh[wave * 64 + lane] = h2v;
  __syncthreads();
  f32x2 hh0 = h2sh[0 * 64 + lane];
  f32x2 hh1 = h2sh[1 * 64 + lane];
  f32x2 hh2 = h2sh[2 * 64 + lane];
  f32x2 hh3 = h2sh[3 * 64 + lane];

  // ---- cooperative beta matmul: this wave owns columns
  // [wave*256, wave*256+256); lane owns 4 cols (one float4) for all 8 rows.
  const int cbase = wave * 64 + lane;  // float4 index within a 1024-col row
  f32x2 acc[4][4];
  {
    const float4 b3v = ((const float4*)b3b)[cbase];
#pragma unroll
    for (int rp = 0; rp < 4; ++rp) {
      acc[rp][0] = f32x2{b3v.x, b3v.x};
      acc[rp][1] = f32x2{b3v.y, b3v.y};
      acc[rp][2] = f32x2{b3v.z, b3v.z};
      acc[rp][3] = f32x2{b3v.w, b3v.w};
    }
  }
  {
    const float4* w34 = (const float4*)W3b;
#pragma unroll 4
    for (int m = 0; m < 64; ++m) {
      const float4 wv = w34[(m << 8) + cbase];
      const f32x2 h0 = f32x2{rdlane(hh0.x, m), rdlane(hh0.y, m)};
      const f32x2 h1 = f32x2{rdlane(hh1.x, m), rdlane(hh1.y, m)};
      const f32x2 h2_ = f32x2{rdlane(hh2.x, m), rdlane(hh2.y, m)};
      const f32x2 h3 = f32x2{rdlane(hh3.x, m), rdlane(hh3.y, m)};
      acc[0][0] = pk_fma(f32x2{wv.x, wv.x}, h0, acc[0][0]);
      acc[0][1] = pk_fma(f32x2{wv.y, wv.y}, h0, acc[0][1]);
      acc[0][2] = pk_fma(f32x2{wv.z, wv.z}, h0, acc[0][2]);
      acc[0][3] = pk_fma(f32x2{wv.w, wv.w}, h0, acc[0][3]);
      acc[1][0] = pk_fma(f32x2{wv.x, wv.x}, h1, acc[1][0]);
      acc[1][1] = pk_fma(f32x2{wv.y, wv.y}, h1, acc[1][1]);
      acc[1][2] = pk_fma(f32x2{wv.z, wv.z}, h1, acc[1][2]);
      acc[1][3] = pk_fma(f32x2{wv.w, wv.w}, h1, acc[1][3]);
      acc[2][0] = pk_fma(f32x2{wv.x, wv.x}, h2_, acc[2][0]);
      acc[2][1] = pk_fma(f32x2{wv.y, wv.y}, h2_, acc[2][1]);
      acc[2][2] = pk_fma(f32x2{wv.z, wv.z}, h2_, acc[2][2]);
      acc[2][3] = pk_fma(f32x2{wv.w, wv.w}, h2_, acc[2][3]);
      acc[3][0] = pk_fma(f32x2{wv.x, wv.x}, h3, acc[3][0]);
      acc[3][1] = pk_fma(f32x2{wv.y, wv.y}, h3, acc[3][1]);
      acc[3][2] = pk_fma(f32x2{wv.z, wv.z}, h3, acc[3][2]);
      acc[3][3] = pk_fma(f32x2{wv.w, wv.w}, h3, acc[3][3]);
    }
  }
  // redistribute logits: row-major [8][1024] in LDS, contiguous b128 writes
#pragma unroll
  for (int rp = 0; rp < 4; ++rp) {
    float4 ex, ey;
    ex.x = acc[rp][0].x; ex.y = acc[rp][1].x; ex.z = acc[rp][2].x; ex.w = acc[rp][3].x;
    ey.x = acc[rp][0].y; ey.y = acc[rp][1].y; ey.z = acc[rp][2].y; ey.w = acc[rp][3].y;
    ((float4*)(lgt + (2 * rp) * N_ORB))[cbase] = ex;
    ((float4*)(lgt + (2 * rp + 1) * N_ORB))[cbase] = ey;
  }
  __syncthreads();

  // readback own rows in the lane->cols lane*16+j layout
  f32x2 w[16];
  {
    const float4* lr0 = (const float4*)(lgt + (2 * wave) * N_ORB);
    const float4* lr1 = (const float4*)(lgt + (2 * wave + 1) * N_ORB);
#pragma unroll
    for (int q = 0; q < 4; ++q) {
      const float4 a = lr0[lane * 4 + q];
      const float4 b = lr1[lane * 4 + q];
      w[4 * q + 0] = f32x2{a.x, b.x};
      w[4 * q + 1] = f32x2{a.y, b.y};
      w[4 * q + 2] = f32x2{a.z, b.z};
      w[4 * q + 3] = f32x2{a.w, b.w};
    }
  }
  // + base_b + gumbel (prefetched) -> keys; selection only
  unsigned kb0[16], kb1[16];
  {
    const float4* bb4 = (const float4*)bb;
#pragma unroll
    for (int q = 0; q < 4; ++q) {
      float4 b = bb4[lane * 4 + q];
      const float4 g0 = gb0[q];
      const float4 g1 = gb1[q];
      kb0[4 * q + 0] = fkey(w[4 * q + 0].x + b.x + g0.x);
      kb1[4 * q + 0] = fkey(w[4 * q + 0].y + b.x + g1.x);
      kb0[4 * q + 1] = fkey(w[4 * q + 1].x + b.y + g0.y);
      kb1[4 * q + 1] = fkey(w[4 * q + 1].y + b.y + g1.y);
      kb0[4 * q + 2] = fkey(w[4 * q + 2].x + b.z + g0.z);
      kb1[4 * q + 2] = fkey(w[4 * q + 2].y + b.z + g1.z);
      kb0[4 * q + 3] = fkey(w[4 * q + 3].x + b.w + g0.w);
      kb1[4 * q + 3] = fkey(w[4 * q + 3].y + b.w + g1.w);
    }
  }
  unsigned bm0, bm1;
  top32_mask2u(kb0, kb1, lane, bm0, bm1);

  if (active) write_half(out + (size_t)row0 * (2 * N_ORB) + N_ORB, bm0, lane);
  if (have1)
    write_half(out + (size_t)(row0 + 1) * (2 * N_ORB) + N_ORB, bm1, lane);
}

extern "C" void kernel_launch(void* const* d_in, const int* in_sizes, int n_in,
                              void* d_out, int out_size, void* d_ws, size_t ws_size,
                              hipStream_t stream) {
  const float* ba  = (const float*)d_in[0];
  const float* W1a = (const float*)d_in[1];
  const float* b1a = (const float*)d_in[2];
  const float* W2a = (const float*)d_in[3];
  const float* b2a = (const float*)d_in[4];
  const float* W3a = (const float*)d_in[5];
  const float* b3a = (const float*)d_in[6];
  const float* bb  = (const float*)d_in[7];
  const float* Wc  = (const float*)d_in[8];
  const float* bc  = (const float*)d_in[9];
  const float* W1b = (const float*)d_in[10];
  const float* b1b = (const float*)d_in[11];
  const float* W2b = (const float*)d_in[12];
  const float* b2b = (const float*)d_in[13];
  const float* W3b = (const float*)d_in[14];
  const float* b3b = (const float*)d_in[15];
  const float* ga  = (const float*)d_in[16];
  const float* gbt = (const float*)d_in[17];
  const int B = in_sizes[16] / N_ORB;
  float* ws = (float*)d_ws;

  hipLaunchKernelGGL(pcfs_pre1, dim3(256), dim3(256), 0, stream,
                     ba, W1a, b1a, bb, W1b, ws);
  hipLaunchKernelGGL(pcfs_pre2a, dim3(1), dim3(64), 0, stream,
                     W2a, b2a, ws);
  hipLaunchKernelGGL(pcfs_pre2b, dim3(4), dim3(256), 0, stream,
                     ba, W3a, b3a, ws);
  const int pairs = (B + 1) / 2;
  hipLaunchKernelGGL(pcfs_sampler, dim3((pairs + 3) / 4), dim3(256), 0, stream,
                     ws, Wc, bc, W1b, b1b, W2b, b2b, W3b, b3b, bb,
                     ga, gbt, (float*)d_out, B);
}